// Round 21
// baseline (105.648 us; speedup 1.0000x reference)
//
#include <hip/hip_runtime.h>
#include <math.h>

#define BB 4
#define SS 2048
#define DD 768
#define HH 12
#define KK 64

#define NPROJ 3
#define HK    (HH * KK)          // 768
#define NCOLS (NPROJ * HK)       // 2304
#define MROWS (BB * SS)          // 8192
#define PER   (BB * HH * SS * KK)  // 6291456 elements per proj

typedef __attribute__((ext_vector_type(8))) short bf16x8;
typedef __attribute__((ext_vector_type(4))) short bf16x4;
typedef __attribute__((ext_vector_type(4))) float f32x4;
typedef __attribute__((ext_vector_type(16))) float f32x16;

static __device__ __forceinline__ short f2bf(float f) {
  union { float f; unsigned u; } v;
  v.f = f;
  unsigned r = (v.u + 0x7fff + ((v.u >> 16) & 1)) >> 16;  // RNE
  return (short)r;
}

static __device__ __forceinline__ unsigned cvtpk(float lo, float hi) {
  unsigned r;
  asm("v_cvt_pk_bf16_f32 %0, %1, %2" : "=v"(r) : "v"(lo), "v"(hi));
  return r;
}

static __device__ __forceinline__ float fexp2(float x) {
#if __has_builtin(__builtin_amdgcn_exp2f)
  return __builtin_amdgcn_exp2f(x);
#else
  return exp2f(x);
#endif
}

// ---------------------------------------------------------------------------
// Fused input conversion (frozen from R19).
// ---------------------------------------------------------------------------
__global__ __launch_bounds__(256) void conv_xw(const float* __restrict__ x,
                                               const float* __restrict__ Wq,
                                               const float* __restrict__ Wk,
                                               const float* __restrict__ Wv,
                                               short* __restrict__ xbf,
                                               short* __restrict__ wbf) {
  int bid = blockIdx.x;
  if (bid < 3072) {
    int i = (bid * 256 + threadIdx.x) * 8;
    float4 v0 = *(const float4*)(x + i);
    float4 v1 = *(const float4*)(x + i + 4);
    bf16x8 o = {f2bf(v0.x), f2bf(v0.y), f2bf(v0.z), f2bf(v0.w),
                f2bf(v1.x), f2bf(v1.y), f2bf(v1.z), f2bf(v1.w)};
    *(bf16x8*)(xbf + i) = o;
  } else {
    int o = (bid - 3072) * 256 + threadIdx.x;  // 2304*768 total
    int n = o / DD, d = o % DD;
    int proj = n / HK;
    int hk = n % HK;
    int h = hk >> 6, k = hk & 63;
    const float* W = proj == 0 ? Wq : (proj == 1 ? Wk : Wv);
    float v = W[(size_t)h * DD * KK + (size_t)d * KK + k];
    if (proj == 0) v *= 0.125f * 1.44269504088896340736f;
    wbf[o] = f2bf(v);
  }
}

// ---------------------------------------------------------------------------
// QKV GEMM v3: BK=32, TRIPLE-buffered (48 KB -> 3 blocks/CU), ONE barrier
// per K-iter (R19 safety argument: buffer overwritten at iter t was last
// read at t-2, fenced by barrier t-1). Counted vmcnt(4). XCD swizzle v2.
// 64B-row XOR swizzle: read slot lg^((li>>1)&3), stage slot
// (lane&3)^((lane>>3)&3) -- exact 2-way (free).
// Coalesced Q/K epilogue through LDS; V transposed Vt[bh][k][s].
// ---------------------------------------------------------------------------
__global__ __launch_bounds__(256) void qkv_gemm(const short* __restrict__ xbf,
                                                const short* __restrict__ wbf,
                                                short* __restrict__ qkv) {
  __shared__ short smem[3 * 8192];      // 3 bufs x (A 4096 + B 4096) = 48 KB
  int bid = blockIdx.x;
  int i = bid >> 3;
  int bm = (bid & 7) * 8 + (i & 7);     // XCD-exclusive M-row group
  int bn = i >> 3;                      // 0..17
  int m0 = bm * 128, n0 = bn * 128;
  int tid = threadIdx.x, lane = tid & 63, wid = tid >> 6;
  int li = lane & 15, lg = lane >> 4;
  int wm = wid >> 1, wn = wid & 1;

  f32x4 acc[4][4];
  #pragma unroll
  for (int mi = 0; mi < 4; ++mi)
    #pragma unroll
    for (int ni = 0; ni < 4; ++ni)
      acc[mi][ni] = (f32x4){0.f, 0.f, 0.f, 0.f};

  int srow2 = lane >> 2;                         // row within 16-row chunk
  int sg8 = ((lane & 3) ^ ((lane >> 3) & 3)) * 8;  // inv-swizzled k-slice
  int rsw = ((li >> 1) & 3);                     // read-side swizzle term

  // STAGE buffer bf_ for K-step kt_: 4 loads/thread (2 A + 2 B)
  #define GSTAGE(bf_, kt_)                                                     \
    {                                                                          \
      short* As_ = smem + (bf_) * 8192;                                        \
      short* Bs_ = As_ + 4096;                                                 \
      _Pragma("unroll")                                                        \
      for (int j = 0; j < 2; ++j) {                                            \
        int row = wid * 32 + j * 16 + srow2;                                   \
        int eb = wid * 1024 + j * 512;                                         \
        __builtin_amdgcn_global_load_lds(                                      \
            (const __attribute__((address_space(1))) void*)(                   \
                xbf + (size_t)(m0 + row) * DD + (kt_) * 32 + sg8),             \
            (__attribute__((address_space(3))) void*)(As_ + eb), 16, 0, 0);    \
        __builtin_amdgcn_global_load_lds(                                      \
            (const __attribute__((address_space(1))) void*)(                   \
                wbf + (size_t)(n0 + row) * DD + (kt_) * 32 + sg8),             \
            (__attribute__((address_space(3))) void*)(Bs_ + eb), 16, 0, 0);    \
      }                                                                        \
    }

  GSTAGE(0, 0);

  int cur = 0;
  for (int kt = 0; kt < DD / 32; ++kt) {
    if (kt + 1 < DD / 32) {
      int nxt = cur + 1 == 3 ? 0 : cur + 1;
      GSTAGE(nxt, kt + 1);
      asm volatile("s_waitcnt vmcnt(4)" ::: "memory");  // cur buf landed
    } else {
      asm volatile("s_waitcnt vmcnt(0)" ::: "memory");
    }
    __builtin_amdgcn_s_barrier();   // cur staged; all waves past compute kt-2

    const short* As = smem + cur * 8192;
    const short* Bs = As + 4096;
    bf16x8 af[4], bfr[4];
    #pragma unroll
    for (int mi = 0; mi < 4; ++mi)
      af[mi] = *(const bf16x8*)(As + (wm * 64 + mi * 16 + li) * 32 +
                                ((lg ^ rsw) << 3));
    #pragma unroll
    for (int ni = 0; ni < 4; ++ni)
      bfr[ni] = *(const bf16x8*)(Bs + (wn * 64 + ni * 16 + li) * 32 +
                                 ((lg ^ rsw) << 3));
    #pragma unroll
    for (int mi = 0; mi < 4; ++mi)
      #pragma unroll
      for (int ni = 0; ni < 4; ++ni)
        acc[mi][ni] = __builtin_amdgcn_mfma_f32_16x16x32_bf16(
            af[mi], bfr[ni], acc[mi][ni], 0, 0, 0);
    cur = cur + 1 == 3 ? 0 : cur + 1;
  }
  #undef GSTAGE

  int proj = n0 / HK;
  int hk0 = n0 % HK;
  int h0 = hk0 >> 6;

  if (proj == 2) {
    #pragma unroll
    for (int ni = 0; ni < 4; ++ni) {
      int ncol = n0 + wn * 64 + ni * 16 + li;
      int hk = ncol % HK;
      int h = hk >> 6, k = hk & 63;
      #pragma unroll
      for (int mi = 0; mi < 4; ++mi) {
        int mrow0 = m0 + wm * 64 + mi * 16 + lg * 4;
        int b = mrow0 >> 11, s = mrow0 & 2047;
        bf16x4 o = {f2bf(acc[mi][ni][0]), f2bf(acc[mi][ni][1]),
                    f2bf(acc[mi][ni][2]), f2bf(acc[mi][ni][3])};
        *(bf16x4*)(qkv + 2 * (size_t)PER +
                   ((size_t)(b * HH + h) * KK + k) * SS + s) = o;
      }
    }
  } else {
    short* Cs = smem;                 // 128 x 128 shorts = 32 KB (fits 48)
    __syncthreads();                  // all waves out of the main loop
    #pragma unroll
    for (int ni = 0; ni < 4; ++ni) {
      int nl = wn * 64 + ni * 16 + li;
      int slot = nl >> 3, nlo = nl & 7;
      #pragma unroll
      for (int mi = 0; mi < 4; ++mi) {
        int ml0 = wm * 64 + mi * 16 + lg * 4;
        #pragma unroll
        for (int r = 0; r < 4; ++r) {
          int ml = ml0 + r;
          Cs[ml * 128 + ((slot ^ (ml & 7)) << 3) + nlo] =
              f2bf(acc[mi][ni][r]);
        }
      }
    }
    __syncthreads();
    int sl = tid & 7;
    #pragma unroll
    for (int p = 0; p < 8; ++p) {
      int line = p * 32 + (tid >> 3);
      int hh = line >> 7, mrow = line & 127;
      bf16x8 v = *(const bf16x8*)&Cs[mrow * 128 +
                                     (((hh * 8 + sl) ^ (mrow & 7)) << 3)];
      int gm = m0 + mrow;
      int b = gm >> 11, s = gm & 2047;
      *(bf16x8*)(qkv + (size_t)proj * PER +
                 ((size_t)(b * HH + h0 + hh) * SS + s) * KK + sl * 8) = v;
    }
  }
}

// ---------------------------------------------------------------------------
// One 32x32 flash sub-step (frozen), no max tracking, swizzled LDS.
// sc C-layout: col=lane&31=q, row=key=crow(r,hi)=(r&3)+8*(r>>2)+4*hi.
// ---------------------------------------------------------------------------
static __device__ __forceinline__ void attn_step_lds(
    const short* Kt, const short* Vv, const bf16x8* qf, bool diag, int h2,
    int lq, int hi, float& lsum, f32x16& acc0, f32x16& acc1) {
  int x7 = lq & 7;
  bf16x8 kf[4];
  {
    int kbase = (h2 * 32 + lq) * 64;
    #pragma unroll
    for (int c = 0; c < 4; ++c)
      kf[c] = *(const bf16x8*)&Kt[kbase + (((2 * c + hi) ^ x7)) * 8];
  }
  bf16x8 vf[2][2];
  #pragma unroll
  for (int m2 = 0; m2 < 2; ++m2) {
    int vbase = (32 * m2 + lq) * 64;
    #pragma unroll
    for (int c = 0; c < 2; ++c)
      vf[m2][c] =
          *(const bf16x8*)&Vv[vbase + (((h2 * 4 + 2 * c + hi) ^ x7)) * 8];
  }

  f32x16 sc;
  #pragma unroll
  for (int r = 0; r < 16; ++r) sc[r] = 0.f;
  #pragma unroll
  for (int c = 0; c < 4; ++c)
    sc = __builtin_amdgcn_mfma_f32_32x32x16_bf16(kf[c], qf[c], sc, 0, 0, 0);

  if (diag) {
    #pragma unroll
    for (int r = 0; r < 16; ++r) {
      int crow = (r & 3) + 8 * (r >> 2) + 4 * hi;
      if (crow > lq) sc[r] = -INFINITY;   // exp2(-inf) = 0
    }
  }

  float p[16];
  #pragma unroll
  for (int r = 0; r < 16; ++r) p[r] = fexp2(sc[r]);

  float s8[8];
  #pragma unroll
  for (int r = 0; r < 8; ++r) s8[r] = p[2 * r] + p[2 * r + 1];
  lsum += ((s8[0] + s8[1]) + (s8[2] + s8[3])) +
          ((s8[4] + s8[5]) + (s8[6] + s8[7]));

  bf16x8 pf[2];
  #pragma unroll
  for (int c = 0; c < 2; ++c) {
    unsigned a0u = cvtpk(p[8 * c + 0], p[8 * c + 1]);
    unsigned b0u = cvtpk(p[8 * c + 4], p[8 * c + 5]);
    unsigned a1u = cvtpk(p[8 * c + 2], p[8 * c + 3]);
    unsigned b1u = cvtpk(p[8 * c + 6], p[8 * c + 7]);
    asm volatile("v_permlane32_swap_b32 %0, %1" : "+v"(a0u), "+v"(b0u));
    asm volatile("v_permlane32_swap_b32 %0, %1" : "+v"(a1u), "+v"(b1u));
    union { unsigned u[4]; bf16x8 v; } pu;
    pu.u[0] = a0u; pu.u[1] = a1u; pu.u[2] = b0u; pu.u[3] = b1u;
    pf[c] = pu.v;
  }

  acc0 = __builtin_amdgcn_mfma_f32_32x32x16_bf16(vf[0][0], pf[0], acc0, 0, 0, 0);
  acc0 = __builtin_amdgcn_mfma_f32_32x32x16_bf16(vf[0][1], pf[1], acc0, 0, 0, 0);
  acc1 = __builtin_amdgcn_mfma_f32_32x32x16_bf16(vf[1][0], pf[0], acc1, 0, 0, 0);
  acc1 = __builtin_amdgcn_mfma_f32_32x32x16_bf16(vf[1][1], pf[1], acc1, 0, 0, 0);
}

// ---------------------------------------------------------------------------
// Flash attention, triple-buffered, one barrier per tile (frozen from R19).
// ---------------------------------------------------------------------------
__global__ __launch_bounds__(256) void attn_kernel(
    const short* __restrict__ qkv, float* __restrict__ out) {
  __shared__ short tile[3][8192];  // [buf][ K: 0..4095 | V: 4096..8191 ]

  int tid = threadIdx.x;
  int wid = tid >> 6, lane = tid & 63;
  int bid = blockIdx.x;
  int qb = 15 - bid / 48;            // heavy q-blocks first
  int bh = bid % 48;
  int b = bh / HH, h = bh % HH;
  int Q0 = qb * 128;
  int s0w = Q0 + 32 * wid;           // wave's first query
  int lq = lane & 31, hi = lane >> 5;

  const short* Qb = qkv + (size_t)bh * SS * KK;
  const short* Kb = qkv + (size_t)PER + (size_t)bh * SS * KK;
  const short* Vt = qkv + 2 * (size_t)PER + (size_t)bh * KK * SS;

  bf16x8 qf[4];
  #pragma unroll
  for (int c = 0; c < 4; ++c)
    qf[c] = *(const bf16x8*)(Qb + (size_t)(s0w + lq) * KK + c * 16 + hi * 8);

  f32x16 acc0, acc1;
  #pragma unroll
  for (int r = 0; r < 16; ++r) { acc0[r] = 0.f; acc1[r] = 0.f; }
  float lsum = 0.f;

  int srow = tid >> 3;               // 0..31
  int sl2 = (tid & 7) ^ (srow & 7);  // inverse-swizzled global slot
  int ldsK = wid * 512;              // wave-uniform LDS short offset

  const int tmax = 2 * qb + 1;       // 64-key tiles: 0..tmax

  #define STAGE(bf_, t_)                                                       \
    {                                                                          \
      int kt0s = (t_) * 64;                                                    \
      _Pragma("unroll")                                                        \
      for (int i = 0; i < 2; ++i) {                                            \
        __builtin_amdgcn_global_load_lds(                                      \
            (const __attribute__((address_space(1))) void*)(                   \
                Kb + (size_t)(kt0s + i * 32 + srow) * KK + sl2 * 8),           \
            (__attribute__((address_space(3))) void*)(&tile[bf_][i * 2048 +    \
                                                                 ldsK]),       \
            16, 0, 0);                                                         \
        __builtin_amdgcn_global_load_lds(                                      \
            (const __attribute__((address_space(1))) void*)(                   \
                Vt + (size_t)(i * 32 + srow) * SS + kt0s + sl2 * 8),           \
            (__attribute__((address_space(3))) void*)(&tile[bf_][4096 +        \
                                                                 i * 2048 +    \
                                                                 ldsK]),       \
            16, 0, 0);                                                         \
      }                                                                        \
    }

  STAGE(0, 0);

  int cur = 0;
  for (int t = 0; t <= tmax; ++t) {
    if (t < tmax) {
      int nxt = cur + 1 == 3 ? 0 : cur + 1;
      STAGE(nxt, t + 1);
      asm volatile("s_waitcnt vmcnt(4)" ::: "memory");
    } else {
      asm volatile("s_waitcnt vmcnt(0)" ::: "memory");
    }
    __builtin_amdgcn_s_barrier();   // tile[cur] staged; all waves past t-1

    const short* Kt = &tile[cur][0];
    const short* Vv = &tile[cur][4096];
    int kt0 = t * 64;
    #pragma unroll
    for (int h2 = 0; h2 < 2; ++h2) {
      int ks = kt0 + 32 * h2;
      if (ks <= s0w)
        attn_step_lds(Kt, Vv, qf, ks == s0w, h2, lq, hi, lsum, acc0, acc1);
    }
    cur = cur + 1 == 3 ? 0 : cur + 1;
  }
  #undef STAGE

  // ---- epilogue: combine the two key-halves of lsum, direct store ----
  lsum += __shfl_xor(lsum, 32, 64);
  float inv = 1.0f / lsum;
  float* orow = out + ((size_t)(b * SS + s0w + lq)) * HK + h * KK;
  #pragma unroll
  for (int g = 0; g < 4; ++g) {
    int kd = 8 * g + 4 * hi;
    float4 w0 = {acc0[g * 4 + 0] * inv, acc0[g * 4 + 1] * inv,
                 acc0[g * 4 + 2] * inv, acc0[g * 4 + 3] * inv};
    float4 w1 = {acc1[g * 4 + 0] * inv, acc1[g * 4 + 1] * inv,
                 acc1[g * 4 + 2] * inv, acc1[g * 4 + 3] * inv};
    *(float4*)(orow + kd) = w0;
    *(float4*)(orow + 32 + kd) = w1;
  }
}

// ---------------------------------------------------------------------------
extern "C" void kernel_launch(void* const* d_in, const int* in_sizes, int n_in,
                              void* d_out, int out_size, void* d_ws,
                              size_t ws_size, hipStream_t stream) {
  const float* x  = (const float*)d_in[0];
  const float* Wq = (const float*)d_in[1];
  const float* Wk = (const float*)d_in[2];
  const float* Wv = (const float*)d_in[3];
  short* ws  = (short*)d_ws;
  short* qkv = ws;                       // 3 * PER shorts
  short* xbf = ws + (size_t)3 * PER;     // MROWS*DD shorts
  short* wbf = xbf + (size_t)MROWS * DD; // NCOLS*DD shorts
  float* o   = (float*)d_out;

  conv_xw<<<3072 + (NCOLS * DD) / 256, 256, 0, stream>>>(x, Wq, Wk, Wv, xbf,
                                                         wbf);
  qkv_gemm<<<(MROWS / 128) * (NCOLS / 128), 256, 0, stream>>>(xbf, wbf, qkv);
  attn_kernel<<<48 * 16, 256, 0, stream>>>(ws, o);
}

// Round 22
// 96.072 us; speedup vs baseline: 1.0997x; 1.0997x over previous
//
#include <hip/hip_runtime.h>
#include <math.h>

#define BB 4
#define SS 2048
#define DD 768
#define HH 12
#define KK 64

#define NPROJ 3
#define HK    (HH * KK)          // 768
#define NCOLS (NPROJ * HK)       // 2304
#define MROWS (BB * SS)          // 8192
#define PER   (BB * HH * SS * KK)  // 6291456 elements per proj

typedef __attribute__((ext_vector_type(8))) short bf16x8;
typedef __attribute__((ext_vector_type(4))) short bf16x4;
typedef __attribute__((ext_vector_type(4))) float f32x4;
typedef __attribute__((ext_vector_type(16))) float f32x16;

static __device__ __forceinline__ short f2bf(float f) {
  union { float f; unsigned u; } v;
  v.f = f;
  unsigned r = (v.u + 0x7fff + ((v.u >> 16) & 1)) >> 16;  // RNE
  return (short)r;
}

static __device__ __forceinline__ unsigned cvtpk(float lo, float hi) {
  unsigned r;
  asm("v_cvt_pk_bf16_f32 %0, %1, %2" : "=v"(r) : "v"(lo), "v"(hi));
  return r;
}

static __device__ __forceinline__ float fexp2(float x) {
#if __has_builtin(__builtin_amdgcn_exp2f)
  return __builtin_amdgcn_exp2f(x);
#else
  return exp2f(x);
#endif
}

// ---------------------------------------------------------------------------
// Fused input conversion (frozen from R19).
// ---------------------------------------------------------------------------
__global__ __launch_bounds__(256) void conv_xw(const float* __restrict__ x,
                                               const float* __restrict__ Wq,
                                               const float* __restrict__ Wk,
                                               const float* __restrict__ Wv,
                                               short* __restrict__ xbf,
                                               short* __restrict__ wbf) {
  int bid = blockIdx.x;
  if (bid < 3072) {
    int i = (bid * 256 + threadIdx.x) * 8;
    float4 v0 = *(const float4*)(x + i);
    float4 v1 = *(const float4*)(x + i + 4);
    bf16x8 o = {f2bf(v0.x), f2bf(v0.y), f2bf(v0.z), f2bf(v0.w),
                f2bf(v1.x), f2bf(v1.y), f2bf(v1.z), f2bf(v1.w)};
    *(bf16x8*)(xbf + i) = o;
  } else {
    int o = (bid - 3072) * 256 + threadIdx.x;  // 2304*768 total
    int n = o / DD, d = o % DD;
    int proj = n / HK;
    int hk = n % HK;
    int h = hk >> 6, k = hk & 63;
    const float* W = proj == 0 ? Wq : (proj == 1 ? Wk : Wv);
    float v = W[(size_t)h * DD * KK + (size_t)d * KK + k];
    if (proj == 0) v *= 0.125f * 1.44269504088896340736f;
    wbf[o] = f2bf(v);
  }
}

// ---------------------------------------------------------------------------
// QKV GEMM (REVERTED to R15, the proven 38.5 us version): BK=64, 2-phase
// double-buffered, counted vmcnt(8), XCD swizzle v2 (exclusive bm groups),
// XOR-swizzled LDS, coalesced Q/K epilogue, V transposed Vt[bh][k][s].
// ---------------------------------------------------------------------------
__global__ __launch_bounds__(256) void qkv_gemm(const short* __restrict__ xbf,
                                                const short* __restrict__ wbf,
                                                short* __restrict__ qkv) {
  __shared__ short smem[4 * 128 * 64];  // buf0A|buf0B|buf1A|buf1B = 64 KB
  int bid = blockIdx.x;
  int i = bid >> 3;
  int bm = (bid & 7) * 8 + (i & 7);     // XCD-exclusive M-row group
  int bn = i >> 3;                      // 0..17
  int m0 = bm * 128, n0 = bn * 128;
  int tid = threadIdx.x, lane = tid & 63, wid = tid >> 6;
  int li = lane & 15, lg = lane >> 4;
  int wm = wid >> 1, wn = wid & 1;

  f32x4 acc[4][4];
  #pragma unroll
  for (int mi = 0; mi < 4; ++mi)
    #pragma unroll
    for (int ni = 0; ni < 4; ++ni)
      acc[mi][ni] = (f32x4){0.f, 0.f, 0.f, 0.f};

  int rowoff = lane >> 3;
  int kpsw = ((lane & 7) ^ rowoff) * 8;

  #define GSTAGE(bf_, kt_)                                                     \
    {                                                                          \
      short* As_ = smem + (bf_) * 16384;                                       \
      short* Bs_ = As_ + 8192;                                                 \
      _Pragma("unroll")                                                        \
      for (int j = 0; j < 4; ++j) {                                            \
        int eb = wid * 2048 + j * 512;                                         \
        int row = (eb >> 6) + rowoff;                                          \
        __builtin_amdgcn_global_load_lds(                                      \
            (const __attribute__((address_space(1))) void*)(                   \
                xbf + (size_t)(m0 + row) * DD + (kt_) * 64 + kpsw),            \
            (__attribute__((address_space(3))) void*)(As_ + eb), 16, 0, 0);    \
        __builtin_amdgcn_global_load_lds(                                      \
            (const __attribute__((address_space(1))) void*)(                   \
                wbf + (size_t)(n0 + row) * DD + (kt_) * 64 + kpsw),            \
            (__attribute__((address_space(3))) void*)(Bs_ + eb), 16, 0, 0);    \
      }                                                                        \
    }

  GSTAGE(0, 0);

  for (int kt = 0; kt < DD / 64; ++kt) {
    int cur = kt & 1;
    if (kt + 1 < DD / 64) {
      GSTAGE(cur ^ 1, kt + 1);
      asm volatile("s_waitcnt vmcnt(8)" ::: "memory");
    } else {
      asm volatile("s_waitcnt vmcnt(0)" ::: "memory");
    }
    __builtin_amdgcn_s_barrier();

    const short* As = smem + cur * 16384;
    const short* Bs = As + 8192;
    #pragma unroll
    for (int kk = 0; kk < 2; ++kk) {
      bf16x8 af[4], bfr[4];
      #pragma unroll
      for (int mi = 0; mi < 4; ++mi)
        af[mi] = *(const bf16x8*)(As + (wm * 64 + mi * 16 + li) * 64 +
                                  (((kk * 4 + lg) ^ (li & 7)) << 3));
      #pragma unroll
      for (int ni = 0; ni < 4; ++ni)
        bfr[ni] = *(const bf16x8*)(Bs + (wn * 64 + ni * 16 + li) * 64 +
                                   (((kk * 4 + lg) ^ (li & 7)) << 3));
      #pragma unroll
      for (int mi = 0; mi < 4; ++mi)
        #pragma unroll
        for (int ni = 0; ni < 4; ++ni)
          acc[mi][ni] = __builtin_amdgcn_mfma_f32_16x16x32_bf16(
              af[mi], bfr[ni], acc[mi][ni], 0, 0, 0);
    }
    __builtin_amdgcn_s_barrier();
  }
  #undef GSTAGE

  int proj = n0 / HK;
  int hk0 = n0 % HK;
  int h0 = hk0 >> 6;

  if (proj == 2) {
    #pragma unroll
    for (int ni = 0; ni < 4; ++ni) {
      int ncol = n0 + wn * 64 + ni * 16 + li;
      int hk = ncol % HK;
      int h = hk >> 6, k = hk & 63;
      #pragma unroll
      for (int mi = 0; mi < 4; ++mi) {
        int mrow0 = m0 + wm * 64 + mi * 16 + lg * 4;
        int b = mrow0 >> 11, s = mrow0 & 2047;
        bf16x4 o = {f2bf(acc[mi][ni][0]), f2bf(acc[mi][ni][1]),
                    f2bf(acc[mi][ni][2]), f2bf(acc[mi][ni][3])};
        *(bf16x4*)(qkv + 2 * (size_t)PER +
                   ((size_t)(b * HH + h) * KK + k) * SS + s) = o;
      }
    }
  } else {
    short* Cs = smem;
    __syncthreads();
    #pragma unroll
    for (int ni = 0; ni < 4; ++ni) {
      int nl = wn * 64 + ni * 16 + li;
      int slot = nl >> 3, nlo = nl & 7;
      #pragma unroll
      for (int mi = 0; mi < 4; ++mi) {
        int ml0 = wm * 64 + mi * 16 + lg * 4;
        #pragma unroll
        for (int r = 0; r < 4; ++r) {
          int ml = ml0 + r;
          Cs[ml * 128 + ((slot ^ (ml & 7)) << 3) + nlo] =
              f2bf(acc[mi][ni][r]);
        }
      }
    }
    __syncthreads();
    int sl = tid & 7;
    #pragma unroll
    for (int p = 0; p < 8; ++p) {
      int line = p * 32 + (tid >> 3);
      int hh = line >> 7, mrow = line & 127;
      bf16x8 v = *(const bf16x8*)&Cs[mrow * 128 +
                                     (((hh * 8 + sl) ^ (mrow & 7)) << 3)];
      int gm = m0 + mrow;
      int b = gm >> 11, s = gm & 2047;
      *(bf16x8*)(qkv + (size_t)proj * PER +
                 ((size_t)(b * HH + h0 + hh) * SS + s) * KK + sl * 8) = v;
    }
  }
}

// ---------------------------------------------------------------------------
// One 32x32 flash sub-step, no max tracking, swizzled LDS, with T5
// s_setprio(1) around the MFMA clusters (clean A/B on the R19 structure:
// independent latency-bound blocks = the regime where m191 measured +4-7%).
// sc C-layout: col=lane&31=q, row=key=crow(r,hi)=(r&3)+8*(r>>2)+4*hi.
// ---------------------------------------------------------------------------
static __device__ __forceinline__ void attn_step_lds(
    const short* Kt, const short* Vv, const bf16x8* qf, bool diag, int h2,
    int lq, int hi, float& lsum, f32x16& acc0, f32x16& acc1) {
  int x7 = lq & 7;
  bf16x8 kf[4];
  {
    int kbase = (h2 * 32 + lq) * 64;
    #pragma unroll
    for (int c = 0; c < 4; ++c)
      kf[c] = *(const bf16x8*)&Kt[kbase + (((2 * c + hi) ^ x7)) * 8];
  }
  bf16x8 vf[2][2];
  #pragma unroll
  for (int m2 = 0; m2 < 2; ++m2) {
    int vbase = (32 * m2 + lq) * 64;
    #pragma unroll
    for (int c = 0; c < 2; ++c)
      vf[m2][c] =
          *(const bf16x8*)&Vv[vbase + (((h2 * 4 + 2 * c + hi) ^ x7)) * 8];
  }

  f32x16 sc;
  #pragma unroll
  for (int r = 0; r < 16; ++r) sc[r] = 0.f;
  __builtin_amdgcn_s_setprio(1);
  #pragma unroll
  for (int c = 0; c < 4; ++c)
    sc = __builtin_amdgcn_mfma_f32_32x32x16_bf16(kf[c], qf[c], sc, 0, 0, 0);
  __builtin_amdgcn_s_setprio(0);

  if (diag) {
    #pragma unroll
    for (int r = 0; r < 16; ++r) {
      int crow = (r & 3) + 8 * (r >> 2) + 4 * hi;
      if (crow > lq) sc[r] = -INFINITY;   // exp2(-inf) = 0
    }
  }

  float p[16];
  #pragma unroll
  for (int r = 0; r < 16; ++r) p[r] = fexp2(sc[r]);

  float s8[8];
  #pragma unroll
  for (int r = 0; r < 8; ++r) s8[r] = p[2 * r] + p[2 * r + 1];
  lsum += ((s8[0] + s8[1]) + (s8[2] + s8[3])) +
          ((s8[4] + s8[5]) + (s8[6] + s8[7]));

  bf16x8 pf[2];
  #pragma unroll
  for (int c = 0; c < 2; ++c) {
    unsigned a0u = cvtpk(p[8 * c + 0], p[8 * c + 1]);
    unsigned b0u = cvtpk(p[8 * c + 4], p[8 * c + 5]);
    unsigned a1u = cvtpk(p[8 * c + 2], p[8 * c + 3]);
    unsigned b1u = cvtpk(p[8 * c + 6], p[8 * c + 7]);
    asm volatile("v_permlane32_swap_b32 %0, %1" : "+v"(a0u), "+v"(b0u));
    asm volatile("v_permlane32_swap_b32 %0, %1" : "+v"(a1u), "+v"(b1u));
    union { unsigned u[4]; bf16x8 v; } pu;
    pu.u[0] = a0u; pu.u[1] = a1u; pu.u[2] = b0u; pu.u[3] = b1u;
    pf[c] = pu.v;
  }

  __builtin_amdgcn_s_setprio(1);
  acc0 = __builtin_amdgcn_mfma_f32_32x32x16_bf16(vf[0][0], pf[0], acc0, 0, 0, 0);
  acc0 = __builtin_amdgcn_mfma_f32_32x32x16_bf16(vf[0][1], pf[1], acc0, 0, 0, 0);
  acc1 = __builtin_amdgcn_mfma_f32_32x32x16_bf16(vf[1][0], pf[0], acc1, 0, 0, 0);
  acc1 = __builtin_amdgcn_mfma_f32_32x32x16_bf16(vf[1][1], pf[1], acc1, 0, 0, 0);
  __builtin_amdgcn_s_setprio(0);
}

// ---------------------------------------------------------------------------
// Flash attention, triple-buffered, one barrier per tile (frozen from R19).
// ---------------------------------------------------------------------------
__global__ __launch_bounds__(256) void attn_kernel(
    const short* __restrict__ qkv, float* __restrict__ out) {
  __shared__ short tile[3][8192];  // [buf][ K: 0..4095 | V: 4096..8191 ]

  int tid = threadIdx.x;
  int wid = tid >> 6, lane = tid & 63;
  int bid = blockIdx.x;
  int qb = 15 - bid / 48;            // heavy q-blocks first
  int bh = bid % 48;
  int b = bh / HH, h = bh % HH;
  int Q0 = qb * 128;
  int s0w = Q0 + 32 * wid;           // wave's first query
  int lq = lane & 31, hi = lane >> 5;

  const short* Qb = qkv + (size_t)bh * SS * KK;
  const short* Kb = qkv + (size_t)PER + (size_t)bh * SS * KK;
  const short* Vt = qkv + 2 * (size_t)PER + (size_t)bh * KK * SS;

  bf16x8 qf[4];
  #pragma unroll
  for (int c = 0; c < 4; ++c)
    qf[c] = *(const bf16x8*)(Qb + (size_t)(s0w + lq) * KK + c * 16 + hi * 8);

  f32x16 acc0, acc1;
  #pragma unroll
  for (int r = 0; r < 16; ++r) { acc0[r] = 0.f; acc1[r] = 0.f; }
  float lsum = 0.f;

  int srow = tid >> 3;               // 0..31
  int sl2 = (tid & 7) ^ (srow & 7);  // inverse-swizzled global slot
  int ldsK = wid * 512;              // wave-uniform LDS short offset

  const int tmax = 2 * qb + 1;       // 64-key tiles: 0..tmax

  #define STAGE(bf_, t_)                                                       \
    {                                                                          \
      int kt0s = (t_) * 64;                                                    \
      _Pragma("unroll")                                                        \
      for (int i = 0; i < 2; ++i) {                                            \
        __builtin_amdgcn_global_load_lds(                                      \
            (const __attribute__((address_space(1))) void*)(                   \
                Kb + (size_t)(kt0s + i * 32 + srow) * KK + sl2 * 8),           \
            (__attribute__((address_space(3))) void*)(&tile[bf_][i * 2048 +    \
                                                                 ldsK]),       \
            16, 0, 0);                                                         \
        __builtin_amdgcn_global_load_lds(                                      \
            (const __attribute__((address_space(1))) void*)(                   \
                Vt + (size_t)(i * 32 + srow) * SS + kt0s + sl2 * 8),           \
            (__attribute__((address_space(3))) void*)(&tile[bf_][4096 +        \
                                                                 i * 2048 +    \
                                                                 ldsK]),       \
            16, 0, 0);                                                         \
      }                                                                        \
    }

  STAGE(0, 0);

  int cur = 0;
  for (int t = 0; t <= tmax; ++t) {
    if (t < tmax) {
      int nxt = cur + 1 == 3 ? 0 : cur + 1;
      STAGE(nxt, t + 1);
      asm volatile("s_waitcnt vmcnt(4)" ::: "memory");
    } else {
      asm volatile("s_waitcnt vmcnt(0)" ::: "memory");
    }
    __builtin_amdgcn_s_barrier();   // tile[cur] staged; all waves past t-1

    const short* Kt = &tile[cur][0];
    const short* Vv = &tile[cur][4096];
    int kt0 = t * 64;
    #pragma unroll
    for (int h2 = 0; h2 < 2; ++h2) {
      int ks = kt0 + 32 * h2;
      if (ks <= s0w)
        attn_step_lds(Kt, Vv, qf, ks == s0w, h2, lq, hi, lsum, acc0, acc1);
    }
    cur = cur + 1 == 3 ? 0 : cur + 1;
  }
  #undef STAGE

  // ---- epilogue: combine the two key-halves of lsum, direct store ----
  lsum += __shfl_xor(lsum, 32, 64);
  float inv = 1.0f / lsum;
  float* orow = out + ((size_t)(b * SS + s0w + lq)) * HK + h * KK;
  #pragma unroll
  for (int g = 0; g < 4; ++g) {
    int kd = 8 * g + 4 * hi;
    float4 w0 = {acc0[g * 4 + 0] * inv, acc0[g * 4 + 1] * inv,
                 acc0[g * 4 + 2] * inv, acc0[g * 4 + 3] * inv};
    float4 w1 = {acc1[g * 4 + 0] * inv, acc1[g * 4 + 1] * inv,
                 acc1[g * 4 + 2] * inv, acc1[g * 4 + 3] * inv};
    *(float4*)(orow + kd) = w0;
    *(float4*)(orow + 32 + kd) = w1;
  }
}

// ---------------------------------------------------------------------------
extern "C" void kernel_launch(void* const* d_in, const int* in_sizes, int n_in,
                              void* d_out, int out_size, void* d_ws,
                              size_t ws_size, hipStream_t stream) {
  const float* x  = (const float*)d_in[0];
  const float* Wq = (const float*)d_in[1];
  const float* Wk = (const float*)d_in[2];
  const float* Wv = (const float*)d_in[3];
  short* ws  = (short*)d_ws;
  short* qkv = ws;                       // 3 * PER shorts
  short* xbf = ws + (size_t)3 * PER;     // MROWS*DD shorts
  short* wbf = xbf + (size_t)MROWS * DD; // NCOLS*DD shorts
  float* o   = (float*)d_out;

  conv_xw<<<3072 + (NCOLS * DD) / 256, 256, 0, stream>>>(x, Wq, Wk, Wv, xbf,
                                                         wbf);
  qkv_gemm<<<(MROWS / 128) * (NCOLS / 128), 256, 0, stream>>>(xbf, wbf, qkv);
  attn_kernel<<<48 * 16, 256, 0, stream>>>(ws, o);
}

// Round 23
// 93.536 us; speedup vs baseline: 1.1295x; 1.0271x over previous
//
#include <hip/hip_runtime.h>
#include <math.h>

#define BB 4
#define SS 2048
#define DD 768
#define HH 12
#define KK 64

#define NPROJ 3
#define HK    (HH * KK)          // 768
#define NCOLS (NPROJ * HK)       // 2304
#define MROWS (BB * SS)          // 8192
#define PER   (BB * HH * SS * KK)  // 6291456 elements per proj

typedef __attribute__((ext_vector_type(8))) short bf16x8;
typedef __attribute__((ext_vector_type(4))) short bf16x4;
typedef __attribute__((ext_vector_type(4))) float f32x4;
typedef __attribute__((ext_vector_type(16))) float f32x16;

static __device__ __forceinline__ short f2bf(float f) {
  union { float f; unsigned u; } v;
  v.f = f;
  unsigned r = (v.u + 0x7fff + ((v.u >> 16) & 1)) >> 16;  // RNE
  return (short)r;
}

static __device__ __forceinline__ unsigned cvtpk(float lo, float hi) {
  unsigned r;
  asm("v_cvt_pk_bf16_f32 %0, %1, %2" : "=v"(r) : "v"(lo), "v"(hi));
  return r;
}

static __device__ __forceinline__ float fexp2(float x) {
#if __has_builtin(__builtin_amdgcn_exp2f)
  return __builtin_amdgcn_exp2f(x);
#else
  return exp2f(x);
#endif
}

// ---------------------------------------------------------------------------
// Fused input conversion (frozen from R19).
// ---------------------------------------------------------------------------
__global__ __launch_bounds__(256) void conv_xw(const float* __restrict__ x,
                                               const float* __restrict__ Wq,
                                               const float* __restrict__ Wk,
                                               const float* __restrict__ Wv,
                                               short* __restrict__ xbf,
                                               short* __restrict__ wbf) {
  int bid = blockIdx.x;
  if (bid < 3072) {
    int i = (bid * 256 + threadIdx.x) * 8;
    float4 v0 = *(const float4*)(x + i);
    float4 v1 = *(const float4*)(x + i + 4);
    bf16x8 o = {f2bf(v0.x), f2bf(v0.y), f2bf(v0.z), f2bf(v0.w),
                f2bf(v1.x), f2bf(v1.y), f2bf(v1.z), f2bf(v1.w)};
    *(bf16x8*)(xbf + i) = o;
  } else {
    int o = (bid - 3072) * 256 + threadIdx.x;  // 2304*768 total
    int n = o / DD, d = o % DD;
    int proj = n / HK;
    int hk = n % HK;
    int h = hk >> 6, k = hk & 63;
    const float* W = proj == 0 ? Wq : (proj == 1 ? Wk : Wv);
    float v = W[(size_t)h * DD * KK + (size_t)d * KK + k];
    if (proj == 0) v *= 0.125f * 1.44269504088896340736f;
    wbf[o] = f2bf(v);
  }
}

// ---------------------------------------------------------------------------
// QKV GEMM (R15-proven): BK=64, 2-phase double-buffered, counted vmcnt(8),
// XCD swizzle v2 (exclusive bm groups), XOR-swizzled LDS, coalesced Q/K
// epilogue, V transposed Vt[bh][k][s].
// ---------------------------------------------------------------------------
__global__ __launch_bounds__(256) void qkv_gemm(const short* __restrict__ xbf,
                                                const short* __restrict__ wbf,
                                                short* __restrict__ qkv) {
  __shared__ short smem[4 * 128 * 64];  // buf0A|buf0B|buf1A|buf1B = 64 KB
  int bid = blockIdx.x;
  int i = bid >> 3;
  int bm = (bid & 7) * 8 + (i & 7);     // XCD-exclusive M-row group
  int bn = i >> 3;                      // 0..17
  int m0 = bm * 128, n0 = bn * 128;
  int tid = threadIdx.x, lane = tid & 63, wid = tid >> 6;
  int li = lane & 15, lg = lane >> 4;
  int wm = wid >> 1, wn = wid & 1;

  f32x4 acc[4][4];
  #pragma unroll
  for (int mi = 0; mi < 4; ++mi)
    #pragma unroll
    for (int ni = 0; ni < 4; ++ni)
      acc[mi][ni] = (f32x4){0.f, 0.f, 0.f, 0.f};

  int rowoff = lane >> 3;
  int kpsw = ((lane & 7) ^ rowoff) * 8;

  #define GSTAGE(bf_, kt_)                                                     \
    {                                                                          \
      short* As_ = smem + (bf_) * 16384;                                       \
      short* Bs_ = As_ + 8192;                                                 \
      _Pragma("unroll")                                                        \
      for (int j = 0; j < 4; ++j) {                                            \
        int eb = wid * 2048 + j * 512;                                         \
        int row = (eb >> 6) + rowoff;                                          \
        __builtin_amdgcn_global_load_lds(                                      \
            (const __attribute__((address_space(1))) void*)(                   \
                xbf + (size_t)(m0 + row) * DD + (kt_) * 64 + kpsw),            \
            (__attribute__((address_space(3))) void*)(As_ + eb), 16, 0, 0);    \
        __builtin_amdgcn_global_load_lds(                                      \
            (const __attribute__((address_space(1))) void*)(                   \
                wbf + (size_t)(n0 + row) * DD + (kt_) * 64 + kpsw),            \
            (__attribute__((address_space(3))) void*)(Bs_ + eb), 16, 0, 0);    \
      }                                                                        \
    }

  GSTAGE(0, 0);

  for (int kt = 0; kt < DD / 64; ++kt) {
    int cur = kt & 1;
    if (kt + 1 < DD / 64) {
      GSTAGE(cur ^ 1, kt + 1);
      asm volatile("s_waitcnt vmcnt(8)" ::: "memory");
    } else {
      asm volatile("s_waitcnt vmcnt(0)" ::: "memory");
    }
    __builtin_amdgcn_s_barrier();

    const short* As = smem + cur * 16384;
    const short* Bs = As + 8192;
    #pragma unroll
    for (int kk = 0; kk < 2; ++kk) {
      bf16x8 af[4], bfr[4];
      #pragma unroll
      for (int mi = 0; mi < 4; ++mi)
        af[mi] = *(const bf16x8*)(As + (wm * 64 + mi * 16 + li) * 64 +
                                  (((kk * 4 + lg) ^ (li & 7)) << 3));
      #pragma unroll
      for (int ni = 0; ni < 4; ++ni)
        bfr[ni] = *(const bf16x8*)(Bs + (wn * 64 + ni * 16 + li) * 64 +
                                   (((kk * 4 + lg) ^ (li & 7)) << 3));
      #pragma unroll
      for (int mi = 0; mi < 4; ++mi)
        #pragma unroll
        for (int ni = 0; ni < 4; ++ni)
          acc[mi][ni] = __builtin_amdgcn_mfma_f32_16x16x32_bf16(
              af[mi], bfr[ni], acc[mi][ni], 0, 0, 0);
    }
    __builtin_amdgcn_s_barrier();
  }
  #undef GSTAGE

  int proj = n0 / HK;
  int hk0 = n0 % HK;
  int h0 = hk0 >> 6;

  if (proj == 2) {
    #pragma unroll
    for (int ni = 0; ni < 4; ++ni) {
      int ncol = n0 + wn * 64 + ni * 16 + li;
      int hk = ncol % HK;
      int h = hk >> 6, k = hk & 63;
      #pragma unroll
      for (int mi = 0; mi < 4; ++mi) {
        int mrow0 = m0 + wm * 64 + mi * 16 + lg * 4;
        int b = mrow0 >> 11, s = mrow0 & 2047;
        bf16x4 o = {f2bf(acc[mi][ni][0]), f2bf(acc[mi][ni][1]),
                    f2bf(acc[mi][ni][2]), f2bf(acc[mi][ni][3])};
        *(bf16x4*)(qkv + 2 * (size_t)PER +
                   ((size_t)(b * HH + h) * KK + k) * SS + s) = o;
      }
    }
  } else {
    short* Cs = smem;
    __syncthreads();
    #pragma unroll
    for (int ni = 0; ni < 4; ++ni) {
      int nl = wn * 64 + ni * 16 + li;
      int slot = nl >> 3, nlo = nl & 7;
      #pragma unroll
      for (int mi = 0; mi < 4; ++mi) {
        int ml0 = wm * 64 + mi * 16 + lg * 4;
        #pragma unroll
        for (int r = 0; r < 4; ++r) {
          int ml = ml0 + r;
          Cs[ml * 128 + ((slot ^ (ml & 7)) << 3) + nlo] =
              f2bf(acc[mi][ni][r]);
        }
      }
    }
    __syncthreads();
    int sl = tid & 7;
    #pragma unroll
    for (int p = 0; p < 8; ++p) {
      int line = p * 32 + (tid >> 3);
      int hh = line >> 7, mrow = line & 127;
      bf16x8 v = *(const bf16x8*)&Cs[mrow * 128 +
                                     (((hh * 8 + sl) ^ (mrow & 7)) << 3)];
      int gm = m0 + mrow;
      int b = gm >> 11, s = gm & 2047;
      *(bf16x8*)(qkv + (size_t)proj * PER +
                 ((size_t)(b * HH + h0 + hh) * SS + s) * KK + sl * 8) = v;
    }
  }
}

// ---------------------------------------------------------------------------
// One 32x32 flash sub-step, no max tracking, swizzled LDS (no setprio —
// R21 A/B measured it -4 us on this barrier-synced lockstep structure).
// sc C-layout: col=lane&31=q, row=key=crow(r,hi)=(r&3)+8*(r>>2)+4*hi.
// ---------------------------------------------------------------------------
static __device__ __forceinline__ void attn_step_lds(
    const short* Kt, const short* Vv, const bf16x8* qf, bool diag, int h2,
    int lq, int hi, float& lsum, f32x16& acc0, f32x16& acc1) {
  int x7 = lq & 7;
  bf16x8 kf[4];
  {
    int kbase = (h2 * 32 + lq) * 64;
    #pragma unroll
    for (int c = 0; c < 4; ++c)
      kf[c] = *(const bf16x8*)&Kt[kbase + (((2 * c + hi) ^ x7)) * 8];
  }
  bf16x8 vf[2][2];
  #pragma unroll
  for (int m2 = 0; m2 < 2; ++m2) {
    int vbase = (32 * m2 + lq) * 64;
    #pragma unroll
    for (int c = 0; c < 2; ++c)
      vf[m2][c] =
          *(const bf16x8*)&Vv[vbase + (((h2 * 4 + 2 * c + hi) ^ x7)) * 8];
  }

  f32x16 sc;
  #pragma unroll
  for (int r = 0; r < 16; ++r) sc[r] = 0.f;
  #pragma unroll
  for (int c = 0; c < 4; ++c)
    sc = __builtin_amdgcn_mfma_f32_32x32x16_bf16(kf[c], qf[c], sc, 0, 0, 0);

  if (diag) {
    #pragma unroll
    for (int r = 0; r < 16; ++r) {
      int crow = (r & 3) + 8 * (r >> 2) + 4 * hi;
      if (crow > lq) sc[r] = -INFINITY;   // exp2(-inf) = 0
    }
  }

  float p[16];
  #pragma unroll
  for (int r = 0; r < 16; ++r) p[r] = fexp2(sc[r]);

  float s8[8];
  #pragma unroll
  for (int r = 0; r < 8; ++r) s8[r] = p[2 * r] + p[2 * r + 1];
  lsum += ((s8[0] + s8[1]) + (s8[2] + s8[3])) +
          ((s8[4] + s8[5]) + (s8[6] + s8[7]));

  bf16x8 pf[2];
  #pragma unroll
  for (int c = 0; c < 2; ++c) {
    unsigned a0u = cvtpk(p[8 * c + 0], p[8 * c + 1]);
    unsigned b0u = cvtpk(p[8 * c + 4], p[8 * c + 5]);
    unsigned a1u = cvtpk(p[8 * c + 2], p[8 * c + 3]);
    unsigned b1u = cvtpk(p[8 * c + 6], p[8 * c + 7]);
    asm volatile("v_permlane32_swap_b32 %0, %1" : "+v"(a0u), "+v"(b0u));
    asm volatile("v_permlane32_swap_b32 %0, %1" : "+v"(a1u), "+v"(b1u));
    union { unsigned u[4]; bf16x8 v; } pu;
    pu.u[0] = a0u; pu.u[1] = a1u; pu.u[2] = b0u; pu.u[3] = b1u;
    pf[c] = pu.v;
  }

  acc0 = __builtin_amdgcn_mfma_f32_32x32x16_bf16(vf[0][0], pf[0], acc0, 0, 0, 0);
  acc0 = __builtin_amdgcn_mfma_f32_32x32x16_bf16(vf[0][1], pf[1], acc0, 0, 0, 0);
  acc1 = __builtin_amdgcn_mfma_f32_32x32x16_bf16(vf[1][0], pf[0], acc1, 0, 0, 0);
  acc1 = __builtin_amdgcn_mfma_f32_32x32x16_bf16(vf[1][1], pf[1], acc1, 0, 0, 0);
}

// ---------------------------------------------------------------------------
// Flash attention, triple-buffered, one barrier per tile (frozen from R19).
// ---------------------------------------------------------------------------
__global__ __launch_bounds__(256) void attn_kernel(
    const short* __restrict__ qkv, float* __restrict__ out) {
  __shared__ short tile[3][8192];  // [buf][ K: 0..4095 | V: 4096..8191 ]

  int tid = threadIdx.x;
  int wid = tid >> 6, lane = tid & 63;
  int bid = blockIdx.x;
  int qb = 15 - bid / 48;            // heavy q-blocks first
  int bh = bid % 48;
  int b = bh / HH, h = bh % HH;
  int Q0 = qb * 128;
  int s0w = Q0 + 32 * wid;           // wave's first query
  int lq = lane & 31, hi = lane >> 5;

  const short* Qb = qkv + (size_t)bh * SS * KK;
  const short* Kb = qkv + (size_t)PER + (size_t)bh * SS * KK;
  const short* Vt = qkv + 2 * (size_t)PER + (size_t)bh * KK * SS;

  bf16x8 qf[4];
  #pragma unroll
  for (int c = 0; c < 4; ++c)
    qf[c] = *(const bf16x8*)(Qb + (size_t)(s0w + lq) * KK + c * 16 + hi * 8);

  f32x16 acc0, acc1;
  #pragma unroll
  for (int r = 0; r < 16; ++r) { acc0[r] = 0.f; acc1[r] = 0.f; }
  float lsum = 0.f;

  int srow = tid >> 3;               // 0..31
  int sl2 = (tid & 7) ^ (srow & 7);  // inverse-swizzled global slot
  int ldsK = wid * 512;              // wave-uniform LDS short offset

  const int tmax = 2 * qb + 1;       // 64-key tiles: 0..tmax

  #define STAGE(bf_, t_)                                                       \
    {                                                                          \
      int kt0s = (t_) * 64;                                                    \
      _Pragma("unroll")                                                        \
      for (int i = 0; i < 2; ++i) {                                            \
        __builtin_amdgcn_global_load_lds(                                      \
            (const __attribute__((address_space(1))) void*)(                   \
                Kb + (size_t)(kt0s + i * 32 + srow) * KK + sl2 * 8),           \
            (__attribute__((address_space(3))) void*)(&tile[bf_][i * 2048 +    \
                                                                 ldsK]),       \
            16, 0, 0);                                                         \
        __builtin_amdgcn_global_load_lds(                                      \
            (const __attribute__((address_space(1))) void*)(                   \
                Vt + (size_t)(i * 32 + srow) * SS + kt0s + sl2 * 8),           \
            (__attribute__((address_space(3))) void*)(&tile[bf_][4096 +        \
                                                                 i * 2048 +    \
                                                                 ldsK]),       \
            16, 0, 0);                                                         \
      }                                                                        \
    }

  STAGE(0, 0);

  int cur = 0;
  for (int t = 0; t <= tmax; ++t) {
    if (t < tmax) {
      int nxt = cur + 1 == 3 ? 0 : cur + 1;
      STAGE(nxt, t + 1);
      asm volatile("s_waitcnt vmcnt(4)" ::: "memory");
    } else {
      asm volatile("s_waitcnt vmcnt(0)" ::: "memory");
    }
    __builtin_amdgcn_s_barrier();   // tile[cur] staged; all waves past t-1

    const short* Kt = &tile[cur][0];
    const short* Vv = &tile[cur][4096];
    int kt0 = t * 64;
    #pragma unroll
    for (int h2 = 0; h2 < 2; ++h2) {
      int ks = kt0 + 32 * h2;
      if (ks <= s0w)
        attn_step_lds(Kt, Vv, qf, ks == s0w, h2, lq, hi, lsum, acc0, acc1);
    }
    cur = cur + 1 == 3 ? 0 : cur + 1;
  }
  #undef STAGE

  // ---- epilogue: combine the two key-halves of lsum, direct store ----
  lsum += __shfl_xor(lsum, 32, 64);
  float inv = 1.0f / lsum;
  float* orow = out + ((size_t)(b * SS + s0w + lq)) * HK + h * KK;
  #pragma unroll
  for (int g = 0; g < 4; ++g) {
    int kd = 8 * g + 4 * hi;
    float4 w0 = {acc0[g * 4 + 0] * inv, acc0[g * 4 + 1] * inv,
                 acc0[g * 4 + 2] * inv, acc0[g * 4 + 3] * inv};
    float4 w1 = {acc1[g * 4 + 0] * inv, acc1[g * 4 + 1] * inv,
                 acc1[g * 4 + 2] * inv, acc1[g * 4 + 3] * inv};
    *(float4*)(orow + kd) = w0;
    *(float4*)(orow + 32 + kd) = w1;
  }
}

// ---------------------------------------------------------------------------
extern "C" void kernel_launch(void* const* d_in, const int* in_sizes, int n_in,
                              void* d_out, int out_size, void* d_ws,
                              size_t ws_size, hipStream_t stream) {
  const float* x  = (const float*)d_in[0];
  const float* Wq = (const float*)d_in[1];
  const float* Wk = (const float*)d_in[2];
  const float* Wv = (const float*)d_in[3];
  short* ws  = (short*)d_ws;
  short* qkv = ws;                       // 3 * PER shorts
  short* xbf = ws + (size_t)3 * PER;     // MROWS*DD shorts
  short* wbf = xbf + (size_t)MROWS * DD; // NCOLS*DD shorts
  float* o   = (float*)d_out;

  conv_xw<<<3072 + (NCOLS * DD) / 256, 256, 0, stream>>>(x, Wq, Wk, Wv, xbf,
                                                         wbf);
  qkv_gemm<<<(MROWS / 128) * (NCOLS / 128), 256, 0, stream>>>(xbf, wbf, qkv);
  attn_kernel<<<48 * 16, 256, 0, stream>>>(ws, o);
}